// Round 4
// baseline (10827.906 us; speedup 1.0000x reference)
//
#include <hip/hip_runtime.h>
#include <hip/hip_bf16.h>

#define WN 32768
#define LN 16
#define DN 128
#define WLN (WN * LN)        // 524288
#define NNODES 50000
#define FHN 384

typedef __attribute__((ext_vector_type(8))) short short8;
typedef __attribute__((ext_vector_type(4))) float float4v;
typedef __hip_bfloat16 bf16;

__device__ __forceinline__ float sigm(float x) { return 1.f / (1.f + expf(-x)); }

// ---------- weight prep ----------
// Wcat2 [512][256]: rows 0..255 = (r,z): [wi | wh]; 256..383 = xn: [wi | 0]; 384..511 = hn: [0 | wh]
__global__ __launch_bounds__(256) void wcat2_k(const float* __restrict__ wi,
                                               const float* __restrict__ wh,
                                               bf16* __restrict__ W) {
  int idx = blockIdx.x * 256 + threadIdx.x;  // 512*256
  int n2 = idx >> 8, k2 = idx & 255;
  float v;
  if (n2 < 256)      v = (k2 < 128) ? wi[n2 * 128 + k2] : wh[n2 * 128 + (k2 - 128)];
  else if (n2 < 384) v = (k2 < 128) ? wi[n2 * 128 + k2] : 0.f;
  else               v = (k2 < 128) ? 0.f : wh[(n2 - 128) * 128 + (k2 - 128)];
  W[idx] = (bf16)v;
}

__global__ __launch_bounds__(256) void conv2d_k(const float* __restrict__ src, int ld,
                                                bf16* __restrict__ dst, int cols, int total) {
  int idx = blockIdx.x * 256 + threadIdx.x;
  if (idx >= total) return;
  int r = idx / cols, c = idx - r * cols;
  dst[idx] = (bf16)src[(size_t)r * ld + c];
}

// ---------- RMSNorm -> bf16 ----------
__global__ __launch_bounds__(256) void rmsnorm_bf16_k(const float* __restrict__ X,
                                                      const float* __restrict__ w,
                                                      bf16* __restrict__ out) {
  long row = (long)blockIdx.x * 4 + (threadIdx.x >> 6);
  int lane = threadIdx.x & 63;
  const float* x = X + row * 128;
  float v0 = x[lane], v1 = x[lane + 64];
  float ss = v0 * v0 + v1 * v1;
#pragma unroll
  for (int off = 32; off > 0; off >>= 1) ss += __shfl_down(ss, off);
  ss = __shfl(ss, 0);
  float r = rsqrtf(ss * (1.f / 128.f) + 1e-5f);
  out[row * 128 + lane] = (bf16)(v0 * r * w[lane]);
  out[row * 128 + lane + 64] = (bf16)(v1 * r * w[lane + 64]);
}

// ---------- persistent bidirectional GRU ----------
// grid = WN/64 blocks; each block owns 64 walks, runs all 16 steps, both dirs.
// state kept in LDS (bf16). Out-proj fused (MFMA, accumulates into xbuf fp32).
__device__ __forceinline__ void gate_step(const bf16* __restrict__ hb, long rb, int l,
                                          bf16 (*st)[136], bf16 (*Bs)[40], bf16 (*As)[40],
                                          const bf16* __restrict__ W,
                                          const float* __restrict__ bi,
                                          const float* __restrict__ bh,
                                          int tid, int wave, int lane) {
  float4v acc[32];
#pragma unroll
  for (int i = 0; i < 32; i++) acc[i] = (float4v)(0.f);
  for (int kc = 0; kc < 8; ++kc) {
    __syncthreads();  // protect Bs/As from previous reads
    if (kc < 4) {
#pragma unroll
      for (int i = 0; i < 2; i++) {
        int q = tid + i * 256;
        int row = q >> 3, kq = (q & 7) * 4;
        *(ushort4*)&As[row][kq] = *(const ushort4*)(hb + (rb + row) * 2048 + l * 128 + kc * 32 + kq);
      }
    }
#pragma unroll
    for (int i = 0; i < 8; i++) {  // Bs half 0: W rows 0..255
      int q = tid + i * 256;
      int row = q >> 3, kq = (q & 7) * 4;
      *(ushort4*)&Bs[row][kq] = *(const ushort4*)(W + (size_t)row * 256 + kc * 32 + kq);
    }
    __syncthreads();
    short8 af = (kc < 4) ? *(const short8*)&As[wave * 16 + (lane & 15)][(lane >> 4) * 8]
                         : *(const short8*)&st[wave * 16 + (lane & 15)][(kc - 4) * 32 + (lane >> 4) * 8];
#pragma unroll
    for (int ct = 0; ct < 16; ++ct) {
      short8 bfv = *(const short8*)&Bs[ct * 16 + (lane & 15)][(lane >> 4) * 8];
      acc[ct] = __builtin_amdgcn_mfma_f32_16x16x32_bf16(af, bfv, acc[ct], 0, 0, 0);
    }
    __syncthreads();
#pragma unroll
    for (int i = 0; i < 8; i++) {  // Bs half 1: W rows 256..511
      int q = tid + i * 256;
      int row = q >> 3, kq = (q & 7) * 4;
      *(ushort4*)&Bs[row][kq] = *(const ushort4*)(W + (size_t)(256 + row) * 256 + kc * 32 + kq);
    }
    __syncthreads();
#pragma unroll
    for (int ct = 0; ct < 16; ++ct) {
      short8 bfv = *(const short8*)&Bs[ct * 16 + (lane & 15)][(lane >> 4) * 8];
      acc[16 + ct] = __builtin_amdgcn_mfma_f32_16x16x32_bf16(af, bfv, acc[16 + ct], 0, 0, 0);
    }
  }
  // epilogue: acc[0..7]=r, [8..15]=z, [16..23]=xn, [24..31]=hn
  const int c = lane & 15, qd = lane >> 4;
  float newv[8][4];
#pragma unroll
  for (int ct = 0; ct < 8; ++ct) {
    int d = ct * 16 + c;
    float bR = bi[d] + bh[d];
    float bZ = bi[128 + d] + bh[128 + d];
    float bXN = bi[256 + d], bHN = bh[256 + d];
#pragma unroll
    for (int reg = 0; reg < 4; ++reg) {
      int rl = wave * 16 + qd * 4 + reg;
      float r = sigm(acc[ct][reg] + bR);
      float z = sigm(acc[ct + 8][reg] + bZ);
      float n = tanhf(acc[ct + 16][reg] + bXN + r * (acc[ct + 24][reg] + bHN));
      float hold = (float)st[rl][d];
      newv[ct][reg] = (1.f - z) * n + z * hold;
    }
  }
  __syncthreads();  // all waves done reading old state
#pragma unroll
  for (int ct = 0; ct < 8; ++ct)
#pragma unroll
    for (int reg = 0; reg < 4; ++reg)
      st[wave * 16 + qd * 4 + reg][ct * 16 + c] = (bf16)newv[ct][reg];
  __syncthreads();
}

__device__ __forceinline__ void outproj_step(bf16 (*st)[136], bf16 (*Bs)[40],
                                             const bf16* __restrict__ Wo,
                                             float* __restrict__ xout, long rb, int l,
                                             int tid, int wave, int lane) {
  float4v acc[8];
#pragma unroll
  for (int i = 0; i < 8; i++) acc[i] = (float4v)(0.f);
  for (int kc = 0; kc < 4; ++kc) {
    __syncthreads();
#pragma unroll
    for (int i = 0; i < 4; i++) {
      int q = tid + i * 256;
      int row = q >> 3, kq = (q & 7) * 4;
      *(ushort4*)&Bs[row][kq] = *(const ushort4*)(Wo + (size_t)row * 128 + kc * 32 + kq);
    }
    __syncthreads();
    short8 af = *(const short8*)&st[wave * 16 + (lane & 15)][kc * 32 + (lane >> 4) * 8];
#pragma unroll
    for (int ct = 0; ct < 8; ++ct) {
      short8 bfv = *(const short8*)&Bs[ct * 16 + (lane & 15)][(lane >> 4) * 8];
      acc[ct] = __builtin_amdgcn_mfma_f32_16x16x32_bf16(af, bfv, acc[ct], 0, 0, 0);
    }
  }
  const int c = lane & 15, qd = lane >> 4;
#pragma unroll
  for (int ct = 0; ct < 8; ++ct)
#pragma unroll
    for (int reg = 0; reg < 4; ++reg) {
      long row = rb + wave * 16 + qd * 4 + reg;
      xout[row * 2048 + l * 128 + ct * 16 + c] += acc[ct][reg];
    }
}

__global__ __launch_bounds__(256, 2) void gru_persist_k(
    const bf16* __restrict__ hb, float* __restrict__ xbuf,
    const bf16* __restrict__ Wf, const bf16* __restrict__ Wb,
    const bf16* __restrict__ WoF, const bf16* __restrict__ WoB,
    const float* __restrict__ bi_f, const float* __restrict__ bh_f,
    const float* __restrict__ bi_b, const float* __restrict__ bh_b) {
  __shared__ __attribute__((aligned(16))) bf16 Bs[256][40];   // 20480 B
  __shared__ __attribute__((aligned(16))) bf16 As[64][40];    // 5120 B
  __shared__ __attribute__((aligned(16))) bf16 stf[64][136];  // 17408 B
  __shared__ __attribute__((aligned(16))) bf16 stb[64][136];  // 17408 B  (total 60416)
  const int tid = threadIdx.x, wave = tid >> 6, lane = tid & 63;
  const long rb = (long)blockIdx.x * 64;
  for (int i = tid; i < 4352; i += 256) { ((uint*)stf)[i] = 0; ((uint*)stb)[i] = 0; }
  for (int t = 0; t < 16; ++t) {
    gate_step(hb, rb, t, stf, Bs, As, Wf, bi_f, bh_f, tid, wave, lane);
    outproj_step(stf, Bs, WoF, xbuf, rb, t, tid, wave, lane);
    gate_step(hb, rb, 15 - t, stb, Bs, As, Wb, bi_b, bh_b, tid, wave, lane);
    outproj_step(stb, Bs, WoB, xbuf, rb, 15 - t, tid, wave, lane);
  }
}

// ---------- generic bf16 MFMA GEMM: C[M,128-panel] += A@B^T ----------
template <int EPI>  // 2=add
__global__ __launch_bounds__(256, 2) void mm_bf16_k(const bf16* __restrict__ A, int lda,
                                                    const bf16* __restrict__ B, int ldb,
                                                    float* __restrict__ C, int ldc, int K) {
  __shared__ __attribute__((aligned(16))) bf16 As[64][40];
  __shared__ __attribute__((aligned(16))) bf16 Bs[128][40];
  const int tid = threadIdx.x;
  const int wave = tid >> 6, lane = tid & 63;
  const long rb = (long)blockIdx.x * 64;
  const int nb = blockIdx.y * 128;
  float4v acc[8];
#pragma unroll
  for (int i = 0; i < 8; i++) acc[i] = (float4v)(0.f);
  for (int k0 = 0; k0 < K; k0 += 32) {
#pragma unroll
    for (int i = 0; i < 2; i++) {
      int q = tid + i * 256;
      int row = q >> 3, kq = (q & 7) * 4;
      *(ushort4*)&As[row][kq] = *(const ushort4*)(A + (rb + row) * (size_t)lda + k0 + kq);
    }
#pragma unroll
    for (int i = 0; i < 4; i++) {
      int q = tid + i * 256;
      int row = q >> 3, kq = (q & 7) * 4;
      *(ushort4*)&Bs[row][kq] = *(const ushort4*)(B + (size_t)(nb + row) * ldb + k0 + kq);
    }
    __syncthreads();
    short8 af = *(const short8*)&As[wave * 16 + (lane & 15)][(lane >> 4) * 8];
#pragma unroll
    for (int ct = 0; ct < 8; ++ct) {
      short8 bfv = *(const short8*)&Bs[ct * 16 + (lane & 15)][(lane >> 4) * 8];
      acc[ct] = __builtin_amdgcn_mfma_f32_16x16x32_bf16(af, bfv, acc[ct], 0, 0, 0);
    }
    __syncthreads();
  }
  const int c = lane & 15, qd = lane >> 4;
#pragma unroll
  for (int ct = 0; ct < 8; ++ct) {
    int n = nb + ct * 16 + c;
#pragma unroll
    for (int reg = 0; reg < 4; ++reg) {
      long row = rb + wave * 16 + qd * 4 + reg;
      if (EPI == 2) C[row * ldc + n] += acc[ct][reg];
      else C[row * ldc + n] = acc[ct][reg];
    }
  }
}

// ---------- fused SwiGLU gate (bf16 MFMA) ----------
__global__ __launch_bounds__(256, 2) void ffn_gate2_k(const bf16* __restrict__ A,
                                                      const bf16* __restrict__ W13,
                                                      bf16* __restrict__ U) {
  __shared__ __attribute__((aligned(16))) bf16 As[64][40];
  __shared__ __attribute__((aligned(16))) bf16 Bs[256][40];
  const int tid = threadIdx.x;
  const int wave = tid >> 6, lane = tid & 63;
  const long rb = (long)blockIdx.x * 64;
  const int nb = blockIdx.y * 128;
  float4v a1[8], a3[8];
#pragma unroll
  for (int i = 0; i < 8; i++) { a1[i] = (float4v)(0.f); a3[i] = (float4v)(0.f); }
  for (int k0 = 0; k0 < 128; k0 += 32) {
#pragma unroll
    for (int i = 0; i < 2; i++) {
      int q = tid + i * 256;
      int row = q >> 3, kq = (q & 7) * 4;
      *(ushort4*)&As[row][kq] = *(const ushort4*)(A + (rb + row) * 128 + k0 + kq);
    }
#pragma unroll
    for (int i = 0; i < 8; i++) {
      int q = tid + i * 256;
      int row = q >> 3, kq = (q & 7) * 4;
      int srcrow = (row < 128) ? (nb + row) : (384 + nb + row - 128);
      *(ushort4*)&Bs[row][kq] = *(const ushort4*)(W13 + (size_t)srcrow * 128 + k0 + kq);
    }
    __syncthreads();
    short8 af = *(const short8*)&As[wave * 16 + (lane & 15)][(lane >> 4) * 8];
#pragma unroll
    for (int ct = 0; ct < 8; ++ct) {
      short8 b1 = *(const short8*)&Bs[ct * 16 + (lane & 15)][(lane >> 4) * 8];
      a1[ct] = __builtin_amdgcn_mfma_f32_16x16x32_bf16(af, b1, a1[ct], 0, 0, 0);
      short8 b3 = *(const short8*)&Bs[128 + ct * 16 + (lane & 15)][(lane >> 4) * 8];
      a3[ct] = __builtin_amdgcn_mfma_f32_16x16x32_bf16(af, b3, a3[ct], 0, 0, 0);
    }
    __syncthreads();
  }
  const int c = lane & 15, qd = lane >> 4;
#pragma unroll
  for (int ct = 0; ct < 8; ++ct) {
    int d = nb + ct * 16 + c;
#pragma unroll
    for (int reg = 0; reg < 4; ++reg) {
      long row = rb + wave * 16 + qd * 4 + reg;
      float g = a1[ct][reg];
      U[row * 384 + d] = (bf16)(g * sigm(g) * a3[ct][reg]);
    }
  }
}

// ---------- v-projection: V(bf16) = X(fp32)@B^T + bias, N=128, K=128 ----------
__global__ __launch_bounds__(256, 2) void vproj_k(const float* __restrict__ A,
                                                  const bf16* __restrict__ B,
                                                  const float* __restrict__ bias,
                                                  bf16* __restrict__ V) {
  __shared__ __attribute__((aligned(16))) bf16 As[64][40];
  __shared__ __attribute__((aligned(16))) bf16 Bs[128][40];
  const int tid = threadIdx.x;
  const int wave = tid >> 6, lane = tid & 63;
  const long rb = (long)blockIdx.x * 64;
  float4v acc[8];
#pragma unroll
  for (int i = 0; i < 8; i++) acc[i] = (float4v)(0.f);
  for (int k0 = 0; k0 < 128; k0 += 32) {
#pragma unroll
    for (int i = 0; i < 2; i++) {
      int q = tid + i * 256;
      int row = q >> 3, kq = (q & 7) * 4;
      float4 av = *(const float4*)(A + (rb + row) * 128 + k0 + kq);
      bf16 tmp[4] = {(bf16)av.x, (bf16)av.y, (bf16)av.z, (bf16)av.w};
      *(ushort4*)&As[row][kq] = *(ushort4*)tmp;
    }
#pragma unroll
    for (int i = 0; i < 4; i++) {
      int q = tid + i * 256;
      int row = q >> 3, kq = (q & 7) * 4;
      *(ushort4*)&Bs[row][kq] = *(const ushort4*)(B + (size_t)row * 128 + k0 + kq);
    }
    __syncthreads();
    short8 af = *(const short8*)&As[wave * 16 + (lane & 15)][(lane >> 4) * 8];
#pragma unroll
    for (int ct = 0; ct < 8; ++ct) {
      short8 bfv = *(const short8*)&Bs[ct * 16 + (lane & 15)][(lane >> 4) * 8];
      acc[ct] = __builtin_amdgcn_mfma_f32_16x16x32_bf16(af, bfv, acc[ct], 0, 0, 0);
    }
    __syncthreads();
  }
  const int c = lane & 15, qd = lane >> 4;
#pragma unroll
  for (int ct = 0; ct < 8; ++ct) {
    int n = ct * 16 + c;
    float bv = bias[n];
#pragma unroll
    for (int reg = 0; reg < 4; ++reg) {
      long row = rb + wave * 16 + qd * 4 + reg;
      V[row * 128 + n] = (bf16)(acc[ct][reg] + bv);
    }
  }
}

// ---------- fp32 GEMM (precision-critical small paths) ----------
enum { EPI_STORE = 0, EPI_RELU = 1 };
template <int EPI>
__global__ __launch_bounds__(256) void gemm_k(const float* __restrict__ A, int lda,
                                              const float* __restrict__ B, int ldb,
                                              const float* __restrict__ bias,
                                              float* __restrict__ C, int ldc,
                                              int M, int N, int K) {
  __shared__ float As[16][68];
  __shared__ float Bs[16][68];
  const int tid = threadIdx.x;
  const int bm = blockIdx.x * 64;
  const int bn = blockIdx.y * 64;
  const int lm = tid >> 2;
  const int lk = (tid & 3) << 2;
  const int tm = (tid >> 4) << 2;
  const int tn = (tid & 15) << 2;
  float acc[4][4] = {};
  for (int k0 = 0; k0 < K; k0 += 16) {
    float4 av = make_float4(0.f, 0.f, 0.f, 0.f);
    if (bm + lm < M)
      av = *reinterpret_cast<const float4*>(A + (long)(bm + lm) * lda + k0 + lk);
    As[lk + 0][lm] = av.x; As[lk + 1][lm] = av.y; As[lk + 2][lm] = av.z; As[lk + 3][lm] = av.w;
    float4 bv = *reinterpret_cast<const float4*>(B + (long)(bn + lm) * ldb + k0 + lk);
    Bs[lk + 0][lm] = bv.x; Bs[lk + 1][lm] = bv.y; Bs[lk + 2][lm] = bv.z; Bs[lk + 3][lm] = bv.w;
    __syncthreads();
#pragma unroll
    for (int k = 0; k < 16; k++) {
      float a[4], b[4];
#pragma unroll
      for (int j = 0; j < 4; j++) { a[j] = As[k][tm + j]; b[j] = Bs[k][tn + j]; }
#pragma unroll
      for (int i = 0; i < 4; i++)
#pragma unroll
        for (int j = 0; j < 4; j++) acc[i][j] = fmaf(a[i], b[j], acc[i][j]);
    }
    __syncthreads();
  }
#pragma unroll
  for (int i = 0; i < 4; i++) {
    int gm = bm + tm + i;
    if (gm < M) {
      float* crow = C + (long)gm * ldc + bn;
#pragma unroll
      for (int j = 0; j < 4; j++) {
        float v = acc[i][j] + (bias ? bias[bn + tn + j] : 0.f);
        if (EPI == EPI_RELU) v = fmaxf(v, 0.f);
        crow[tn + j] = v;
      }
    }
  }
}

// ---------- attention: logits ----------
__global__ __launch_bounds__(256) void logits_k(const float* __restrict__ X,
                                                const float* __restrict__ LW,
                                                const float* __restrict__ LB,
                                                float* __restrict__ out) {
  __shared__ float w[1024];
  __shared__ float b[8];
  int tid = threadIdx.x;
  for (int i = tid; i < 1024; i += 256) w[i] = LW[i];
  if (tid < 8) b[tid] = LB[tid];
  __syncthreads();
  long r = (long)blockIdx.x * 32 + (tid >> 3);
  int hh = tid & 7;
  const float* x = X + r * 128;
  const float* wr = w + hh * 128;
  float s = 0.f;
#pragma unroll 16
  for (int k = 0; k < 128; k++) s = fmaf(x[k], wr[k], s);
  out[r * 8 + hh] = s + b[hh];
}

// ---------- CSR build ----------
__global__ __launch_bounds__(256) void count_k(const int* __restrict__ seg, int* __restrict__ cnt) {
  int i = blockIdx.x * 256 + threadIdx.x;  // WLN
  atomicAdd(&cnt[seg[i]], 1);
}

__global__ __launch_bounds__(1024) void scan_k(const int* __restrict__ cnt,
                                               int* __restrict__ offs,
                                               int* __restrict__ cursor) {
  __shared__ int buf[1024];
  __shared__ int carry;
  int tid = threadIdx.x;
  if (tid == 0) carry = 0;
  __syncthreads();
  const int nch = (NNODES + 1023) / 1024;
  for (int c = 0; c < nch; ++c) {
    int i = c * 1024 + tid;
    int v = (i < NNODES) ? cnt[i] : 0;
    buf[tid] = v;
    __syncthreads();
    for (int d = 1; d < 1024; d <<= 1) {
      int t2 = (tid >= d) ? buf[tid - d] : 0;
      __syncthreads();
      buf[tid] += t2;
      __syncthreads();
    }
    int cbase = carry;
    int tot = buf[1023];
    int excl = buf[tid] - v + cbase;
    if (i < NNODES) { offs[i] = excl; cursor[i] = excl; }
    __syncthreads();
    if (tid == 0) carry = cbase + tot;
    __syncthreads();
  }
  if (tid == 0) offs[NNODES] = carry;
}

__global__ __launch_bounds__(256) void fill_k(const int* __restrict__ seg,
                                              int* __restrict__ cursor,
                                              int* __restrict__ idxl) {
  int i = blockIdx.x * 256 + threadIdx.x;  // WLN
  int p = atomicAdd(&cursor[seg[i]], 1);
  idxl[p] = i;
}

// ---------- per-node softmax stats (no atomics) ----------
__global__ __launch_bounds__(256) void nodestat_k(const float* __restrict__ logits,
                                                  const int* __restrict__ offs,
                                                  const int* __restrict__ idxl,
                                                  float* __restrict__ m,
                                                  float* __restrict__ dnm) {
  int t = blockIdx.x * 256 + threadIdx.x;  // node*8+h
  if (t >= NNODES * 8) return;
  int node = t >> 3, h = t & 7;
  int b = offs[node], e2 = offs[node + 1];
  float mx = -1e30f;
  for (int i = b; i < e2; ++i) mx = fmaxf(mx, logits[(long)idxl[i] * 8 + h]);
  float s = 0.f;
  for (int i = b; i < e2; ++i) s += expf(logits[(long)idxl[i] * 8 + h] - mx);
  m[t] = mx;
  dnm[t] = s;
}

// ---------- node-centric gather: node_emb (no atomics) ----------
__global__ __launch_bounds__(256) void gather_k(const bf16* __restrict__ V,
                                                const float* __restrict__ logits,
                                                const float* __restrict__ m,
                                                const float* __restrict__ dnm,
                                                const int* __restrict__ offs,
                                                const int* __restrict__ idxl,
                                                float* __restrict__ node_emb) {
  int node = blockIdx.x * 4 + (threadIdx.x >> 6);  // wave per node, grid = NN/4
  int lane = threadIdx.x & 63;
  int h = lane >> 3;                                // d0=2*lane -> head = lane>>3
  int b = offs[node], e2 = offs[node + 1];
  float mh = m[node * 8 + h];
  float dh = dnm[node * 8 + h] + 1e-9f;
  float acc0 = 0.f, acc1 = 0.f;
  for (int i = b; i < e2; ++i) {
    long v = idxl[i];
    float a = expf(logits[v * 8 + h] - mh) / dh;
    ushort2 p = *(const ushort2*)(V + v * 128 + lane * 2);
    acc0 += a * (float)*(const bf16*)&p.x;
    acc1 += a * (float)*(const bf16*)&p.y;
  }
  node_emb[(long)node * 128 + lane * 2] = acc0;
  node_emb[(long)node * 128 + lane * 2 + 1] = acc1;
}

__global__ __launch_bounds__(256) void gatheradd_k(float* __restrict__ x,
                                                   const float* __restrict__ back,
                                                   const int* __restrict__ seg) {
  long idx = (long)blockIdx.x * 256 + threadIdx.x;
  long i = idx >> 5;
  int d4 = (int)(idx & 31) << 2;
  int s = seg[i];
  float4 xv = *reinterpret_cast<float4*>(x + i * 128 + d4);
  float4 bv = *reinterpret_cast<const float4*>(back + (long)s * 128 + d4);
  xv.x += bv.x; xv.y += bv.y; xv.z += bv.z; xv.w += bv.w;
  *reinterpret_cast<float4*>(x + i * 128 + d4) = xv;
}

__global__ __launch_bounds__(256) void head3_k(const float* __restrict__ H2,
                                               const float* __restrict__ W3,
                                               const float* __restrict__ B3,
                                               float* __restrict__ out, int M) {
  int row = blockIdx.x * 4 + (threadIdx.x >> 6);
  int lane = threadIdx.x & 63;
  if (row >= M) return;
  const float* x = H2 + (long)row * 128;
  float s = x[lane] * W3[lane] + x[lane + 64] * W3[lane + 64];
#pragma unroll
  for (int off = 32; off > 0; off >>= 1) s += __shfl_down(s, off);
  if (lane == 0) out[row] = s + B3[0];
}

// ---------- host ----------
extern "C" void kernel_launch(void* const* d_in, const int* in_sizes, int n_in,
                              void* d_out, int out_size, void* d_ws, size_t ws_size,
                              hipStream_t stream) {
  (void)in_sizes; (void)n_in; (void)out_size; (void)ws_size;
  const float* in_x       = (const float*)d_in[0];
  const int*   seg        = (const int*)d_in[1];
  const float* gru_norm_w = (const float*)d_in[3];
  const float* wi_f       = (const float*)d_in[4];
  const float* wh_f       = (const float*)d_in[5];
  const float* bi_f       = (const float*)d_in[6];
  const float* bh_f       = (const float*)d_in[7];
  const float* wi_b       = (const float*)d_in[8];
  const float* wh_b       = (const float*)d_in[9];
  const float* bi_b       = (const float*)d_in[10];
  const float* bh_b       = (const float*)d_in[11];
  const float* gru_out_w  = (const float*)d_in[12];
  const float* ffn_norm_w = (const float*)d_in[13];
  const float* ffn_w1     = (const float*)d_in[14];
  const float* ffn_w2     = (const float*)d_in[15];
  const float* ffn_w3     = (const float*)d_in[16];
  const float* logit_w    = (const float*)d_in[17];
  const float* logit_b    = (const float*)d_in[18];
  const float* to_node_w  = (const float*)d_in[19];
  const float* to_node_b  = (const float*)d_in[20];
  const float* from_node_w= (const float*)d_in[21];
  const float* from_node_b= (const float*)d_in[22];
  const float* head_w1    = (const float*)d_in[23];
  const float* head_b1    = (const float*)d_in[24];
  const float* head_w2    = (const float*)d_in[25];
  const float* head_b2    = (const float*)d_in[26];
  const float* head_w3    = (const float*)d_in[27];
  const float* head_b3    = (const float*)d_in[28];
  float* out = (float*)d_out;

  // ---- workspace carve-up (float slots), ~580 MB ----
  float* ws = (float*)d_ws;
  size_t o = 0;
  auto alloc = [&](size_t n) { float* p = ws + o; o += (n + 63) & ~(size_t)63; return p; };
  float* xbuf    = alloc((size_t)WLN * 128);           // fp32 residual
  bf16*  hb16    = (bf16*)alloc((size_t)WLN * 64);     // rmsnorm out; reused as V in attention
  bf16*  ub16    = (bf16*)alloc((size_t)WLN / 8 * 192);// FFN chunk intermediate
  float* ebuf    = alloc((size_t)WLN * 8);             // raw logits
  float* mbuf    = alloc((size_t)NNODES * 8);
  float* dnm     = alloc((size_t)NNODES * 8);
  float* node_emb= alloc((size_t)NNODES * 128);
  float* backb   = alloc((size_t)NNODES * 128);
  float* h1b     = alloc((size_t)NNODES * 128);
  float* h2b     = alloc((size_t)NNODES * 128);
  int*   cnt     = (int*)alloc(NNODES);
  int*   offs    = (int*)alloc(NNODES + 1);
  int*   cursor  = (int*)alloc(NNODES);
  int*   idxl    = (int*)alloc(WLN);
  bf16* Wcat2_f  = (bf16*)alloc(512 * 256 / 2);
  bf16* Wcat2_b  = (bf16*)alloc(512 * 256 / 2);
  bf16* WoF      = (bf16*)alloc(128 * 128 / 2);
  bf16* WoB      = (bf16*)alloc(128 * 128 / 2);
  bf16* W13      = (bf16*)alloc(768 * 128 / 2);
  bf16* W2b      = (bf16*)alloc(128 * 384 / 2);
  bf16* WtN      = (bf16*)alloc(128 * 128 / 2);
  bf16* vb16     = hb16;  // alias: V lives in hb16 region during attention

  // ---- weight conversion ----
  hipLaunchKernelGGL(wcat2_k, dim3(512), dim3(256), 0, stream, wi_f, wh_f, Wcat2_f);
  hipLaunchKernelGGL(wcat2_k, dim3(512), dim3(256), 0, stream, wi_b, wh_b, Wcat2_b);
  hipLaunchKernelGGL(conv2d_k, dim3(64), dim3(256), 0, stream, gru_out_w, 256, WoF, 128, 128 * 128);
  hipLaunchKernelGGL(conv2d_k, dim3(64), dim3(256), 0, stream, gru_out_w + 128, 256, WoB, 128, 128 * 128);
  hipLaunchKernelGGL(conv2d_k, dim3(192), dim3(256), 0, stream, ffn_w1, 128, W13, 128, 384 * 128);
  hipLaunchKernelGGL(conv2d_k, dim3(192), dim3(256), 0, stream, ffn_w3, 128, W13 + 384 * 128, 128, 384 * 128);
  hipLaunchKernelGGL(conv2d_k, dim3(192), dim3(256), 0, stream, ffn_w2, 384, W2b, 384, 128 * 384);
  hipLaunchKernelGGL(conv2d_k, dim3(64), dim3(256), 0, stream, to_node_w, 128, WtN, 128, 128 * 128);

  hipMemcpyAsync(xbuf, in_x, (size_t)WLN * 128 * 4, hipMemcpyDeviceToDevice, stream);

  // ---- CSR build (seg is constant across both iterations) ----
  hipMemsetAsync(cnt, 0, NNODES * 4, stream);
  hipLaunchKernelGGL(count_k, dim3(WLN / 256), dim3(256), 0, stream, seg, cnt);
  hipLaunchKernelGGL(scan_k, dim3(1), dim3(1024), 0, stream, cnt, offs, cursor);
  hipLaunchKernelGGL(fill_k, dim3(WLN / 256), dim3(256), 0, stream, seg, cursor, idxl);

  for (int it = 0; it < 2; ++it) {
    // --- GRU block (persistent kernel) ---
    hipLaunchKernelGGL(rmsnorm_bf16_k, dim3(WLN / 4), dim3(256), 0, stream, xbuf, gru_norm_w, hb16);
    hipLaunchKernelGGL(gru_persist_k, dim3(WN / 64), dim3(256), 0, stream,
                       hb16, xbuf, Wcat2_f, Wcat2_b, WoF, WoB, bi_f, bh_f, bi_b, bh_b);

    // --- FFN (8 chunks of 65536 rows) ---
    hipLaunchKernelGGL(rmsnorm_bf16_k, dim3(WLN / 4), dim3(256), 0, stream, xbuf, ffn_norm_w, hb16);
    for (int c = 0; c < 8; ++c) {
      const int CM = WLN / 8;
      hipLaunchKernelGGL(ffn_gate2_k, dim3(CM / 64, 3), dim3(256), 0, stream,
                         hb16 + (size_t)c * CM * 128, W13, ub16);
      hipLaunchKernelGGL((mm_bf16_k<2>), dim3(CM / 64, 1), dim3(256), 0, stream,
                         ub16, 384, W2b, 384, xbuf + (size_t)c * CM * 128, 128, 384);
    }

    // --- attention (CSR node-centric, no atomics) ---
    hipLaunchKernelGGL(logits_k, dim3(WLN / 32), dim3(256), 0, stream, xbuf, logit_w, logit_b, ebuf);
    hipLaunchKernelGGL(vproj_k, dim3(WLN / 64), dim3(256), 0, stream, xbuf, WtN, to_node_b, vb16);
    hipLaunchKernelGGL(nodestat_k, dim3((NNODES * 8 + 255) / 256), dim3(256), 0, stream,
                       ebuf, offs, idxl, mbuf, dnm);
    hipLaunchKernelGGL(gather_k, dim3(NNODES / 4), dim3(256), 0, stream,
                       vb16, ebuf, mbuf, dnm, offs, idxl, node_emb);
    hipLaunchKernelGGL((gemm_k<EPI_STORE>), dim3((NNODES + 63) / 64, 2), dim3(256), 0, stream,
                       node_emb, 128, from_node_w, 128, from_node_b, backb, 128, NNODES, 128, 128);
    hipLaunchKernelGGL(gatheradd_k, dim3(WLN * 32 / 256), dim3(256), 0, stream, xbuf, backb, seg);
  }

  // --- scoring head (fp32) ---
  hipLaunchKernelGGL((gemm_k<EPI_RELU>), dim3((NNODES + 63) / 64, 2), dim3(256), 0, stream,
                     node_emb, 128, head_w1, 128, head_b1, h1b, 128, NNODES, 128, 128);
  hipLaunchKernelGGL((gemm_k<EPI_RELU>), dim3((NNODES + 63) / 64, 2), dim3(256), 0, stream,
                     h1b, 128, head_w2, 128, head_b2, h2b, 128, NNODES, 128, 128);
  hipLaunchKernelGGL(head3_k, dim3((NNODES + 3) / 4), dim3(256), 0, stream, h2b, head_w3, head_b3, out, NNODES);
}